// Round 1
// baseline (247.336 us; speedup 1.0000x reference)
//
#include <hip/hip_runtime.h>

// SSIM, fused single kernel.
// Structure: per (batch, 32-row strip) block; vertical box sums slide down rows
// in registers (11-deep circular buffer, rotation resolved at compile time by
// unrolling the row loop by 11); horizontal box sums read vertical sums from
// LDS with aligned float4 loads + incremental slide; epilogue fused.

static constexpr int WIN_  = 11;
static constexpr int RS    = 32;    // output rows per strip
static constexpr int HI    = 512;
static constexpr int WI    = 512;
static constexpr int HALO  = 8;     // left halo in LDS row (zero padding)
static constexpr int LDSW  = 544;   // 8 + 512 + 24 (right halo + pad)

__global__ __launch_bounds__(256, 2)
void ssim_fused(const float* __restrict__ img, const float* __restrict__ ref,
                const float* __restrict__ drng, float* __restrict__ out)
{
  const int t  = threadIdx.x;
  const int r0 = (int)blockIdx.x * RS;
  const int b  = (int)blockIdx.y;

  __shared__ __align__(16) float sV[5][LDSW];
  // zero once: interior gets overwritten every step, halos stay zero
  for (int k = t; k < 5 * LDSW; k += 256) (&sV[0][0])[k] = 0.0f;

  const float dr  = drng[b];
  const float C1  = (0.01f * dr) * (0.01f * dr);
  const float C2  = (0.03f * dr) * (0.03f * dr);
  const float inv_n    = 1.0f / 121.0f;
  const float cov_norm = 121.0f / 120.0f;

  const size_t base = (size_t)b * ((size_t)HI * WI);
  const float* imgb = img + base;
  const float* refb = ref + base;

  // per-thread vertical state for columns 2t, 2t+1
  float xh[WIN_][2], yh[WIN_][2];
#pragma unroll
  for (int k = 0; k < WIN_; ++k) { xh[k][0]=0.f; xh[k][1]=0.f; yh[k][0]=0.f; yh[k][1]=0.f; }
  float Sx[2]={0.f,0.f}, Sy[2]={0.f,0.f}, Sxx[2]={0.f,0.f}, Syy[2]={0.f,0.f}, Sxy[2]={0.f,0.f};

  __syncthreads();

  for (int ib = 0; ib < 4; ++ib) {
#pragma unroll
    for (int j = 0; j < WIN_; ++j) {
      const int i = ib * WIN_ + j;          // step index; i % 11 == j (compile-time)
      if (i < RS + 10) {
        const int ri = r0 - 5 + i;          // incoming input row
        float xv0=0.f, xv1=0.f, yv0=0.f, yv1=0.f;
        if (ri >= 0 && ri < HI) {
          const float2 xv = *(const float2*)(imgb + (size_t)ri * WI + 2*t);
          const float2 yv = *(const float2*)(refb + (size_t)ri * WI + 2*t);
          xv0=xv.x; xv1=xv.y; yv0=yv.x; yv1=yv.y;
        }
        // add incoming row to vertical sums
        Sx[0]+=xv0; Sx[1]+=xv1; Sy[0]+=yv0; Sy[1]+=yv1;
        Sxx[0]=fmaf(xv0,xv0,Sxx[0]); Sxx[1]=fmaf(xv1,xv1,Sxx[1]);
        Syy[0]=fmaf(yv0,yv0,Syy[0]); Syy[1]=fmaf(yv1,yv1,Syy[1]);
        Sxy[0]=fmaf(xv0,yv0,Sxy[0]); Sxy[1]=fmaf(xv1,yv1,Sxy[1]);

        // publish vertical sums (window rows ri-10..ri)
        const int ci = HALO + 2*t;
        *(float2*)&sV[0][ci] = make_float2(Sx[0],  Sx[1]);
        *(float2*)&sV[1][ci] = make_float2(Sy[0],  Sy[1]);
        *(float2*)&sV[2][ci] = make_float2(Sxx[0], Sxx[1]);
        *(float2*)&sV[3][ci] = make_float2(Syy[0], Syy[1]);
        *(float2*)&sV[4][ci] = make_float2(Sxy[0], Sxy[1]);

        // retire oldest row (register-only; safe before the barrier).
        // slot (j+1)%11 holds step i-10; initial slots are zero so this is a
        // harmless no-op during warm-up.
        {
          const int jo = (j + 1) % WIN_;
          const float xo0=xh[jo][0], xo1=xh[jo][1], yo0=yh[jo][0], yo1=yh[jo][1];
          Sx[0]-=xo0; Sx[1]-=xo1; Sy[0]-=yo0; Sy[1]-=yo1;
          Sxx[0]=fmaf(-xo0,xo0,Sxx[0]); Sxx[1]=fmaf(-xo1,xo1,Sxx[1]);
          Syy[0]=fmaf(-yo0,yo0,Syy[0]); Syy[1]=fmaf(-yo1,yo1,Syy[1]);
          Sxy[0]=fmaf(-xo0,yo0,Sxy[0]); Sxy[1]=fmaf(-xo1,yo1,Sxy[1]);
          xh[j][0]=xv0; xh[j][1]=xv1; yh[j][0]=yv0; yh[j][1]=yv1;
        }

        __syncthreads();

        // phase 2: horizontal window + epilogue, threads 0..127, 4 cols each
        if (i >= 10 && t < 128) {
          const int ro = ri - 5;
          const int c0 = 4 * t;
          float H[5][4];
#pragma unroll
          for (int q = 0; q < 5; ++q) {
            // array idx c0 corresponds to image col c0-8; 16B aligned.
            const float4* p = (const float4*)&sV[q][c0];
            const float4 va = p[0], vb = p[1], vc = p[2], vd = p[3], ve = p[4];
            const float v3=va.w,  v4=vb.x,  v5=vb.y,  v6=vb.z,  v7=vb.w,
                        v8=vc.x,  v9=vc.y,  v10=vc.z, v11=vc.w,
                        v12=vd.x, v13=vd.y, v14=vd.z, v15=vd.w, v16=ve.x;
            const float w0 = ((v3+v4)+(v5+v6)) + ((v7+v8)+(v9+v10)) + ((v11+v12)+v13);
            const float w1 = w0 - v3 + v14;
            const float w2 = w1 - v4 + v15;
            const float w3 = w2 - v5 + v16;
            H[q][0]=w0; H[q][1]=w1; H[q][2]=w2; H[q][3]=w3;
          }
          float4 res;
          float* rp = (float*)&res;
#pragma unroll
          for (int k = 0; k < 4; ++k) {
            const float ux = H[0][k]*inv_n, uy  = H[1][k]*inv_n;
            const float uxx= H[2][k]*inv_n, uyy = H[3][k]*inv_n, uxy = H[4][k]*inv_n;
            const float vx = cov_norm*(uxx - ux*ux);
            const float vy = cov_norm*(uyy - uy*uy);
            const float vxy= cov_norm*(uxy - ux*uy);
            const float A1 = 2.f*ux*uy + C1;
            const float A2 = 2.f*vxy + C2;
            const float B1 = ux*ux + uy*uy + C1;
            const float B2 = vx + vy + C2;
            rp[k] = (A1*A2) * __builtin_amdgcn_rcpf(B1*B2);
          }
          *(float4*)(out + ((size_t)b*HI + ro)*WI + c0) = res;
        }
        __syncthreads();
      }
    }
  }
}

extern "C" void kernel_launch(void* const* d_in, const int* in_sizes, int n_in,
                              void* d_out, int out_size, void* d_ws, size_t ws_size,
                              hipStream_t stream)
{
  const float* img = (const float*)d_in[0];
  const float* ref = (const float*)d_in[1];
  const float* drg = (const float*)d_in[2];
  float* out = (float*)d_out;
  const int B = in_sizes[0] / (HI * WI);   // 64
  dim3 grid(HI / RS, B);
  dim3 block(256);
  hipLaunchKernelGGL(ssim_fused, grid, block, 0, stream, img, ref, drg, out);
}

// Round 3
// 210.950 us; speedup vs baseline: 1.1725x; 1.1725x over previous
//
#include <hip/hip_runtime.h>

// SSIM, barrier-free wave-per-row-strip formulation.
// Each wave owns full image width: 64 lanes x 8 cols = 512. Vertical 11-row
// box sums slide in registers (retiring row re-loaded from global -> L2 hit,
// avoiding an 11-row register history). Horizontal 11-col window needs only
// +/-5 cols from adjacent lanes -> __shfl halo exchange, zero LDS, zero
// __syncthreads. 4096 independent waves (64 batches x 64 strips of 8 rows).
// R2 bugfix: retire guard is (i>=11 && rold>=0) — only subtract rows that
// step i-11 actually added. rold>=0 alone subtracted phantom rows on every
// interior strip.

static constexpr int HI = 512, WI = 512;
static constexpr int RS = 8;              // output rows per wave-strip
static constexpr int STRIPS = HI / RS;    // 64

__device__ __forceinline__ void horiz11(const float v[8], float H[8], int lane) {
  float L[5], R[5];
#pragma unroll
  for (int k = 0; k < 5; ++k) {
    float lt = __shfl(v[3 + k], (lane + 63) & 63);
    L[k] = (lane == 0) ? 0.f : lt;      // image cols -5..-1 are zero-pad
    float rt = __shfl(v[k], (lane + 1) & 63);
    R[k] = (lane == 63) ? 0.f : rt;     // image cols 512..516 are zero-pad
  }
  float h = (((L[0] + L[1]) + (L[2] + L[3])) + ((L[4] + v[0]) + (v[1] + v[2])))
            + ((v[3] + v[4]) + v[5]);
  H[0] = h;
  h = h - L[0] + v[6]; H[1] = h;
  h = h - L[1] + v[7]; H[2] = h;
  h = h - L[2] + R[0]; H[3] = h;
  h = h - L[3] + R[1]; H[4] = h;
  h = h - L[4] + R[2]; H[5] = h;
  h = h - v[0] + R[3]; H[6] = h;
  h = h - v[1] + R[4]; H[7] = h;
}

__global__ __launch_bounds__(256, 3)
void ssim_wave(const float* __restrict__ img, const float* __restrict__ ref,
               const float* __restrict__ drng, float* __restrict__ out)
{
  const int lane = threadIdx.x & 63;
  const int wv   = (int)blockIdx.x * 4 + (threadIdx.x >> 6);
  const int b    = wv >> 6;                       // STRIPS=64 strips/batch
  const int r0   = (wv & (STRIPS - 1)) * RS;
  const int c0   = lane * 8;

  const float dr  = drng[b];
  const float C1  = (0.01f * dr) * (0.01f * dr);
  const float C2  = (0.03f * dr) * (0.03f * dr);
  const float inv_n    = 1.0f / 121.0f;
  const float cov_norm = 121.0f / 120.0f;

  const size_t base = (size_t)b * ((size_t)HI * WI);
  const float* xb = img + base;
  const float* yb = ref + base;
  float*       ob = out + base;

  float Sx[8], Sy[8], Sxx[8], Syy[8], Sxy[8];
#pragma unroll
  for (int c = 0; c < 8; ++c) { Sx[c]=0.f; Sy[c]=0.f; Sxx[c]=0.f; Syy[c]=0.f; Sxy[c]=0.f; }

  for (int i = 0; i < RS + 10; ++i) {
    const int ri = r0 - 5 + i;            // incoming row (window bottom)
    float xn[8], yn[8], xo[8], yo[8];

    if (ri >= 0 && ri < HI) {
      const float4* px = (const float4*)(xb + (size_t)ri * WI + c0);
      const float4* py = (const float4*)(yb + (size_t)ri * WI + c0);
      const float4 a0 = px[0], a1 = px[1];
      const float4 b0 = py[0], b1 = py[1];
      xn[0]=a0.x; xn[1]=a0.y; xn[2]=a0.z; xn[3]=a0.w;
      xn[4]=a1.x; xn[5]=a1.y; xn[6]=a1.z; xn[7]=a1.w;
      yn[0]=b0.x; yn[1]=b0.y; yn[2]=b0.z; yn[3]=b0.w;
      yn[4]=b1.x; yn[5]=b1.y; yn[6]=b1.z; yn[7]=b1.w;
    } else {
#pragma unroll
      for (int c = 0; c < 8; ++c) { xn[c]=0.f; yn[c]=0.f; }
    }

    // row leaving the window: only subtract what step i-11 actually added
    const int rold = ri - 11;
    if (i >= 11 && rold >= 0) {           // rold < HI is implied (rold <= 505)
      const float4* px = (const float4*)(xb + (size_t)rold * WI + c0);
      const float4* py = (const float4*)(yb + (size_t)rold * WI + c0);
      const float4 a0 = px[0], a1 = px[1];
      const float4 b0 = py[0], b1 = py[1];
      xo[0]=a0.x; xo[1]=a0.y; xo[2]=a0.z; xo[3]=a0.w;
      xo[4]=a1.x; xo[5]=a1.y; xo[6]=a1.z; xo[7]=a1.w;
      yo[0]=b0.x; yo[1]=b0.y; yo[2]=b0.z; yo[3]=b0.w;
      yo[4]=b1.x; yo[5]=b1.y; yo[6]=b1.z; yo[7]=b1.w;
    } else {
#pragma unroll
      for (int c = 0; c < 8; ++c) { xo[c]=0.f; yo[c]=0.f; }
    }

#pragma unroll
    for (int c = 0; c < 8; ++c) {
      Sx[c]  += xn[c] - xo[c];
      Sy[c]  += yn[c] - yo[c];
      Sxx[c] = fmaf(xn[c], xn[c], fmaf(-xo[c], xo[c], Sxx[c]));
      Syy[c] = fmaf(yn[c], yn[c], fmaf(-yo[c], yo[c], Syy[c]));
      Sxy[c] = fmaf(xn[c], yn[c], fmaf(-xo[c], yo[c], Sxy[c]));
    }

    if (i >= 10) {
      float H0[8], H1[8], H2[8], H3[8], H4[8];
      horiz11(Sx,  H0, lane);
      horiz11(Sy,  H1, lane);
      horiz11(Sxx, H2, lane);
      horiz11(Syy, H3, lane);
      horiz11(Sxy, H4, lane);

      float res[8];
#pragma unroll
      for (int c = 0; c < 8; ++c) {
        const float ux  = H0[c] * inv_n, uy  = H1[c] * inv_n;
        const float uxx = H2[c] * inv_n, uyy = H3[c] * inv_n, uxy = H4[c] * inv_n;
        const float vx  = cov_norm * (uxx - ux * ux);
        const float vy  = cov_norm * (uyy - uy * uy);
        const float vxy = cov_norm * (uxy - ux * uy);
        const float A1 = 2.f * ux * uy + C1;
        const float A2 = 2.f * vxy + C2;
        const float B1 = ux * ux + uy * uy + C1;
        const float B2 = vx + vy + C2;
        res[c] = (A1 * A2) * __builtin_amdgcn_rcpf(B1 * B2);
      }
      const int ro = ri - 5;
      float4* po = (float4*)(ob + (size_t)ro * WI + c0);
      po[0] = make_float4(res[0], res[1], res[2], res[3]);
      po[1] = make_float4(res[4], res[5], res[6], res[7]);
    }
  }
}

extern "C" void kernel_launch(void* const* d_in, const int* in_sizes, int n_in,
                              void* d_out, int out_size, void* d_ws, size_t ws_size,
                              hipStream_t stream)
{
  const float* img = (const float*)d_in[0];
  const float* ref = (const float*)d_in[1];
  const float* drg = (const float*)d_in[2];
  float* out = (float*)d_out;
  const int B = in_sizes[0] / (HI * WI);          // 64
  const int waves = B * STRIPS;                   // 4096
  dim3 grid(waves / 4);                           // 4 waves (256 thr) per block
  dim3 block(256);
  hipLaunchKernelGGL(ssim_wave, grid, block, 0, stream, img, ref, drg, out);
}

// Round 4
// 199.741 us; speedup vs baseline: 1.2383x; 1.0561x over previous
//
#include <hip/hip_runtime.h>

// SSIM, wave-per-row-strip, branch-free + software-pipelined.
// Each wave owns full image width: 64 lanes x 8 cols = 512. Vertical 11-row
// box sums slide in registers; retiring row re-loaded from global (L2/L3-hot).
// Horizontal 11-col window via __shfl halo exchange (no LDS, no barriers).
// R4: (a) OOB rows read from a zeroed dummy row (wave-uniform pointer select,
// no branches in the load path), (b) explicit depth-2 load pipeline so step
// i+2's 4x dwordx4 loads are in flight while step i computes, (c) RS=16
// (1.63x row amplification vs 2.25x at RS=8). 2048 waves = 8/CU resident.

static constexpr int HI = 512, WI = 512;
static constexpr int RS = 16;             // output rows per wave-strip
static constexpr int STEPS = RS + 10;     // 26
static constexpr int SPB = HI / RS;       // strips per batch = 32

struct R8 { float4 a, b; };

__device__ __forceinline__ R8 ld8(const float* p) {
  R8 r; r.a = ((const float4*)p)[0]; r.b = ((const float4*)p)[1]; return r;
}

__device__ __forceinline__ void horiz11(const float v[8], float H[8], int lane) {
  float L[5], R[5];
#pragma unroll
  for (int k = 0; k < 5; ++k) {
    float lt = __shfl(v[3 + k], (lane + 63) & 63);
    L[k] = (lane == 0) ? 0.f : lt;      // image cols -5..-1 are zero-pad
    float rt = __shfl(v[k], (lane + 1) & 63);
    R[k] = (lane == 63) ? 0.f : rt;     // image cols 512..516 are zero-pad
  }
  float h = (((L[0] + L[1]) + (L[2] + L[3])) + ((L[4] + v[0]) + (v[1] + v[2])))
            + ((v[3] + v[4]) + v[5]);
  H[0] = h;
  h = h - L[0] + v[6]; H[1] = h;
  h = h - L[1] + v[7]; H[2] = h;
  h = h - L[2] + R[0]; H[3] = h;
  h = h - L[3] + R[1]; H[4] = h;
  h = h - L[4] + R[2]; H[5] = h;
  h = h - v[0] + R[3]; H[6] = h;
  h = h - v[1] + R[4]; H[7] = h;
}

__global__ __launch_bounds__(256, 2)
void ssim_wave(const float* __restrict__ img, const float* __restrict__ ref,
               const float* __restrict__ drng, const float* __restrict__ zrow,
               float* __restrict__ out)
{
  const int lane = threadIdx.x & 63;
  const int wv   = (int)blockIdx.x * 4 + (threadIdx.x >> 6);
  const int b    = wv / SPB;
  const int r0   = (wv % SPB) * RS;
  const int c0   = lane * 8;

  const float dr  = drng[b];
  const float C1  = (0.01f * dr) * (0.01f * dr);
  const float C2  = (0.03f * dr) * (0.03f * dr);
  const float inv_n    = 1.0f / 121.0f;
  const float cov_norm = 121.0f / 120.0f;

  const size_t base = (size_t)b * ((size_t)HI * WI);
  const float* xb = img + base;
  const float* yb = ref + base;
  float*       ob = out + base;

  // wave-uniform pointer selects; OOB -> dummy zero row (branch-free loads)
  auto nptr = [&](const float* tb, int i) -> const float* {
    const int ri = r0 - 5 + i;
    return (((unsigned)ri < (unsigned)HI) ? tb + (size_t)ri * WI : zrow) + c0;
  };
  auto optr = [&](const float* tb, int i) -> const float* {
    const int ro = r0 - 16 + i;                  // = ri - 11
    return ((i >= 11 && ro >= 0) ? tb + (size_t)ro * WI : zrow) + c0;
  };

  float Sx[8], Sy[8], Sxx[8], Syy[8], Sxy[8];
#pragma unroll
  for (int c = 0; c < 8; ++c) { Sx[c]=0.f; Sy[c]=0.f; Sxx[c]=0.f; Syy[c]=0.f; Sxy[c]=0.f; }

  // depth-2 pipeline: slot[i&1] holds step i's 4 row-octets
  R8 nx[2], ny[2], ox[2], oy[2];
  nx[0]=ld8(nptr(xb,0)); ny[0]=ld8(nptr(yb,0)); ox[0]=ld8(optr(xb,0)); oy[0]=ld8(optr(yb,0));
  nx[1]=ld8(nptr(xb,1)); ny[1]=ld8(nptr(yb,1)); ox[1]=ld8(optr(xb,1)); oy[1]=ld8(optr(yb,1));

#pragma unroll 2
  for (int i = 0; i < STEPS; ++i) {
    const int s = i & 1;
    // consume current slot into locals
    float xn[8] = { nx[s].a.x, nx[s].a.y, nx[s].a.z, nx[s].a.w,
                    nx[s].b.x, nx[s].b.y, nx[s].b.z, nx[s].b.w };
    float yn[8] = { ny[s].a.x, ny[s].a.y, ny[s].a.z, ny[s].a.w,
                    ny[s].b.x, ny[s].b.y, ny[s].b.z, ny[s].b.w };
    float xo[8] = { ox[s].a.x, ox[s].a.y, ox[s].a.z, ox[s].a.w,
                    ox[s].b.x, ox[s].b.y, ox[s].b.z, ox[s].b.w };
    float yo[8] = { oy[s].a.x, oy[s].a.y, oy[s].a.z, oy[s].a.w,
                    oy[s].b.x, oy[s].b.y, oy[s].b.z, oy[s].b.w };

    // refill slot with step i+2 (issued now, consumed 2 bodies later)
    if (i + 2 < STEPS) {
      nx[s]=ld8(nptr(xb,i+2)); ny[s]=ld8(nptr(yb,i+2));
      ox[s]=ld8(optr(xb,i+2)); oy[s]=ld8(optr(yb,i+2));
    }

#pragma unroll
    for (int c = 0; c < 8; ++c) {
      Sx[c]  += xn[c] - xo[c];
      Sy[c]  += yn[c] - yo[c];
      Sxx[c] = fmaf(xn[c], xn[c], fmaf(-xo[c], xo[c], Sxx[c]));
      Syy[c] = fmaf(yn[c], yn[c], fmaf(-yo[c], yo[c], Syy[c]));
      Sxy[c] = fmaf(xn[c], yn[c], fmaf(-xo[c], yo[c], Sxy[c]));
    }

    if (i >= 10) {
      float H0[8], H1[8], H2[8], H3[8], H4[8];
      horiz11(Sx,  H0, lane);
      horiz11(Sy,  H1, lane);
      horiz11(Sxx, H2, lane);
      horiz11(Syy, H3, lane);
      horiz11(Sxy, H4, lane);

      float res[8];
#pragma unroll
      for (int c = 0; c < 8; ++c) {
        const float ux  = H0[c] * inv_n, uy  = H1[c] * inv_n;
        const float uxx = H2[c] * inv_n, uyy = H3[c] * inv_n, uxy = H4[c] * inv_n;
        const float vx  = cov_norm * (uxx - ux * ux);
        const float vy  = cov_norm * (uyy - uy * uy);
        const float vxy = cov_norm * (uxy - ux * uy);
        const float A1 = 2.f * ux * uy + C1;
        const float A2 = 2.f * vxy + C2;
        const float B1 = ux * ux + uy * uy + C1;
        const float B2 = vx + vy + C2;
        res[c] = (A1 * A2) * __builtin_amdgcn_rcpf(B1 * B2);
      }
      const int ro = r0 + i - 10;
      float4* po = (float4*)(ob + (size_t)ro * WI + c0);
      po[0] = make_float4(res[0], res[1], res[2], res[3]);
      po[1] = make_float4(res[4], res[5], res[6], res[7]);
    }
  }
}

extern "C" void kernel_launch(void* const* d_in, const int* in_sizes, int n_in,
                              void* d_out, int out_size, void* d_ws, size_t ws_size,
                              hipStream_t stream)
{
  const float* img = (const float*)d_in[0];
  const float* ref = (const float*)d_in[1];
  const float* drg = (const float*)d_in[2];
  float* out = (float*)d_out;

  // zero dummy row (d_ws is re-poisoned to 0xAA before every launch)
  hipMemsetAsync(d_ws, 0, (size_t)WI * sizeof(float) + 64, stream);

  const int B = in_sizes[0] / (HI * WI);          // 64
  const int waves = B * SPB;                      // 2048
  dim3 grid(waves / 4);                           // 512 blocks, 4 waves each
  dim3 block(256);
  hipLaunchKernelGGL(ssim_wave, grid, block, 0, stream,
                     img, ref, drg, (const float*)d_ws, out);
}